// Round 6
// baseline (69.601 us; speedup 1.0000x reference)
//
#include <hip/hip_runtime.h>
#include <stdint.h>

// DSN few-shot classifier, MI355X.
// out[q][w] = log_softmax_w( ||P9_w q||^2 ),  query-norm cancels in softmax.
// P9 = P_colspace - u_min u_min^T, so s_w = ||B^T q||^2 - (u_min . q)^2 with
// B = M L^{-T} D^{-1/2} (G = L D L^T) an exact ONB of colspace(M).
//
// R5 structure: TWO kernels.
//  dsn_prep: 80 blocks (one per Upad row). Each block is SELF-SUFFICIENT:
//    stages its way's 10 support rows to LDS, computes the 10x10 Gram
//    (fp64 acc, wave-parallel), solves the subspace problem on lanes 0-9 of
//    wave 0 ONLY (single lane-group: every data-dependent branch is uniform
//    across active lanes -> none of R4's multi-group divergence around
//    ds_bpermute), writes one 1024-elem bf16 row of Upad.
//  dsn_main: unchanged since R1 (proven): MFMA coeffs + log_softmax.
//
// ws layout: [0, 163840) Upad : 80*1024 bf16 (way w -> rows 16w..16w+10).

typedef __attribute__((ext_vector_type(4))) float f32x4;
typedef __attribute__((ext_vector_type(8))) short s16x8;

__device__ __forceinline__ unsigned short f2bf(float f) {
  unsigned int u = __float_as_uint(f);
  u += 0x7FFFu + ((u >> 16) & 1u);   // round-to-nearest-even
  return (unsigned short)(u >> 16);
}

// int64 vs int32 one-hot labels detection (validated R0).
__device__ __forceinline__ bool labels_int64(const int* L) {
  int cnt = 0; bool oddz = true;
  #pragma unroll
  for (int t = 0; t < 20; ++t) {
    int v = L[t];
    if (t & 1) { if (v) oddz = false; }
    else       { if (v) cnt++; }
  }
  return oddz && (cnt == 2);
}

__device__ __forceinline__ int cls_of(const int* L, bool is64, int i) {
  int best = -0x7fffffff, c = 0;
  #pragma unroll
  for (int j = 0; j < 5; ++j) {
    int v = is64 ? L[i * 10 + 2 * j] : L[i * 5 + j];
    if (v > best) { best = v; c = j; }
  }
  return c;
}

// ---------------- Kernel A: fused prep, one block per Upad row -------------
__global__ __launch_bounds__(256) void dsn_prep(const float* __restrict__ support,
                                                const int* __restrict__ labels,
                                                unsigned short* __restrict__ U) {
  int b = blockIdx.x;              // 0..79
  int w = b >> 4, kk = b & 15;
  int t = threadIdx.x;
  unsigned short* Urow = U + b * 1024;
  if (kk >= 11) {                  // zero-pad rows (block-uniform early exit)
    #pragma unroll
    for (int j = 0; j < 4; ++j) Urow[t + 256 * j] = 0;
    return;
  }

  __shared__ float sup[10][1024];  // 40 KB: this way's support rows
  __shared__ float Gsm[100];       // Gram, fp32 (fp64-accumulated)
  __shared__ float Wsm[110];       // rows 0..9: basis coeffs; row 10: v_min/|Mv|
  __shared__ int   ids[10];        // support indices of this way

  // ---- class membership (wave 0) ----
  bool is64 = labels_int64(labels);
  if (t < 64) {
    int myc = (t < 50) ? cls_of(labels, is64, t) : -1;
    unsigned long long mask = __ballot(t < 50 && myc == w);
    if (t < 10) {
      unsigned long long m = mask;
      for (int i2 = 0; i2 < t; ++i2) m &= m - 1;
      ids[t] = __ffsll(m) - 1;
    }
  }
  __syncthreads();

  // ---- stage support rows into LDS (coalesced) ----
  #pragma unroll 1
  for (int s = 0; s < 10; ++s) {
    const float* src = support + (size_t)ids[s] * 1024;
    #pragma unroll
    for (int j = 0; j < 4; ++j) sup[s][t + 256 * j] = src[t + 256 * j];
  }
  __syncthreads();

  // ---- Gram: wave v handles pairs p = v, v+4, ... (fp64 acc, shfl reduce) --
  {
    int wv = t >> 6, lane = t & 63;
    #pragma unroll 1
    for (int p = wv; p < 55; p += 4) {
      int a2 = 0, pp = p;
      while (pp >= 10 - a2) { pp -= 10 - a2; a2++; }
      int b2 = a2 + pp;              // a2 <= b2
      double acc = 0.0;
      #pragma unroll
      for (int i2 = 0; i2 < 16; ++i2) {
        int d = lane + 64 * i2;
        acc += (double)sup[a2][d] * (double)sup[b2][d];
      }
      #pragma unroll
      for (int off = 32; off > 0; off >>= 1) acc += __shfl_xor(acc, off);
      if (lane == 0) {
        Gsm[a2 * 10 + b2] = (float)acc;
        Gsm[b2 * 10 + a2] = (float)acc;
      }
    }
  }
  __syncthreads();

  // ---- subspace solve: lanes 0-9 of wave 0, row-per-lane distributed ----
  // Single lane-group: all data-dependent branches uniform over active lanes.
  if (t < 10) {
    int li = t;                      // my row
    float g[10];
    #pragma unroll
    for (int k = 0; k < 10; ++k) g[k] = Gsm[li * 10 + k];

    float diag = g[0];
    #pragma unroll
    for (int k = 1; k < 10; ++k) diag = (li == k) ? g[k] : diag;
    float asum = 0.f;
    #pragma unroll
    for (int k = 0; k < 10; ++k) asum += fabsf(g[k]);
    float rad = asum - fabsf(diag);
    float loi = diag - rad, hii = diag;
    float lo = loi, hi = hii;
    #pragma unroll
    for (int u = 0; u < 10; ++u) {
      lo = fminf(lo, __shfl(loi, u));
      hi = fminf(hi, __shfl(hii, u));
    }
    lo = fmaxf(lo, 0.f);
    hi = hi + 1.f;

    // bisection on Sylvester inertia (distributed LDL^T), 12 rounds
    #pragma unroll 1
    for (int round = 0; round < 12; ++round) {
      float mid = 0.5f * (lo + hi);
      float a[10];
      #pragma unroll
      for (int k = 0; k < 10; ++k) a[k] = (li == k) ? (g[k] - mid) : g[k];
      int neg = 0;
      #pragma unroll
      for (int j = 0; j < 10; ++j) {
        float dj = __shfl(a[j], j);
        if (fabsf(dj) < 1e-4f) dj = -1e-4f;   // inertia guard
        neg += (dj < 0.f) ? 1 : 0;
        float lij = a[j] / dj;
        #pragma unroll
        for (int k = j + 1; k < 10; ++k) {
          float ajk = __shfl(a[k], j);
          if (li > j) a[k] -= lij * ajk;
        }
      }
      if (neg == 0) lo = mid; else hi = mid;   // uniform across lanes 0-9
    }
    float sigma = lo - (hi - lo) - 0.5f;       // lambda_min - sigma >= ~0.5

    // factorize (G - sigma I) = L D L^T; keep my L-row + my pivot
    float a[10], l[10], dmine = 1.f;
    #pragma unroll
    for (int k = 0; k < 10; ++k) a[k] = (li == k) ? (g[k] - sigma) : g[k];
    #pragma unroll
    for (int j = 0; j < 10; ++j) {
      float dj = __shfl(a[j], j);
      dmine = (li == j) ? dj : dmine;
      float lij = a[j] / dj;
      l[j] = (li > j) ? lij : 0.f;
      #pragma unroll
      for (int k = j + 1; k < 10; ++k) {
        float ajk = __shfl(a[k], j);
        if (li > j) a[k] -= lij * ajk;
      }
    }

    // inverse iteration: y = component li of the iterate
    float y = 1.f;
    #pragma unroll 1
    for (int itr = 0; itr < 4; ++itr) {
      #pragma unroll
      for (int j = 0; j < 9; ++j) {          // forward solve L z = y
        float yj = __shfl(y, j);
        if (li > j) y -= l[j] * yj;
      }
      y /= dmine;
      #pragma unroll
      for (int j = 9; j >= 1; --j) {         // back solve L^T x = z
        float xj = __shfl(y, j);
        float lji = 0.f;
        #pragma unroll
        for (int k = 0; k < j; ++k) {
          float v = __shfl(l[k], j);
          lji = (li == k) ? v : lji;
        }
        if (li < j) y -= lji * xj;
      }
      float am = fabsf(y), mx = am;
      #pragma unroll
      for (int u = 0; u < 10; ++u) mx = fmaxf(mx, __shfl(am, u));
      y *= (1.f / mx);
    }

    // row 10: v / ||M v||, ||M v||^2 = v^T G v
    float gv = 0.f;
    #pragma unroll
    for (int k = 0; k < 10; ++k) gv += g[k] * __shfl(y, k);
    float contrib = gv * y, denom = 0.f;
    #pragma unroll
    for (int u = 0; u < 10; ++u) denom += __shfl(contrib, u);
    float sc = 1.f / sqrtf(denom);
    Wsm[100 + li] = y * sc;

    // factorize G = L D L^T (sigma = 0); keep pivots
    float dv[10];
    #pragma unroll
    for (int k = 0; k < 10; ++k) a[k] = g[k];
    #pragma unroll
    for (int j = 0; j < 10; ++j) {
      float dj = __shfl(a[j], j);
      dv[j] = dj;
      float lij = a[j] / dj;
      l[j] = (li > j) ? lij : 0.f;
      #pragma unroll
      for (int k = j + 1; k < 10; ++k) {
        float ajk = __shfl(a[k], j);
        if (li > j) a[k] -= lij * ajk;
      }
    }

    // X = L^{-T} (lane li holds row li), all 10 columns at once
    float X[10];
    #pragma unroll
    for (int r = 0; r < 10; ++r) X[r] = (li == r) ? 1.f : 0.f;
    #pragma unroll
    for (int j = 9; j >= 1; --j) {
      float lji = 0.f;
      #pragma unroll
      for (int k = 0; k < j; ++k) {
        float v = __shfl(l[k], j);
        lji = (li == k) ? v : lji;
      }
      #pragma unroll
      for (int r = j; r < 10; ++r) {
        float xjr = __shfl(X[r], j);
        if (li < j) X[r] -= lji * xjr;
      }
    }
    // basis r coeffs = col r of L^{-T} D^{-1/2}: Wsm[r*10+s] = X[s][r]/sqrt(d_r)
    #pragma unroll
    for (int r = 0; r < 10; ++r)
      Wsm[r * 10 + li] = X[r] * (1.f / sqrtf(dv[r]));
  }
  __syncthreads();

  // ---- materialize my Upad row from LDS ----
  float wv10[10];
  #pragma unroll
  for (int s = 0; s < 10; ++s) wv10[s] = Wsm[kk * 10 + s];
  #pragma unroll
  for (int j = 0; j < 4; ++j) {
    int d = t + 256 * j;
    float sum = 0.f;
    #pragma unroll
    for (int s = 0; s < 10; ++s) sum += sup[s][d] * wv10[s];
    Urow[d] = f2bf(sum);
  }
}

// ---------------- Kernel B: main — MFMA coeffs + log_softmax ---------------
// 16 queries per wave. A = Upad (5 row-tiles, one per way), B = Q^T fragment.
// D[row=channel][col=query]: col = lane&15, row = (lane>>4)*4 + reg  (m89).
// Row 10 (u_min) lives at lane-group 2, reg 2 -> its square is SUBTRACTED.
__global__ __launch_bounds__(256) void dsn_main(const float* __restrict__ query,
                                                const unsigned short* __restrict__ U,
                                                float* __restrict__ out) {
  int wid  = blockIdx.x * 4 + (threadIdx.x >> 6);
  int lane = threadIdx.x & 63;
  int q0   = wid * 16;
  int qrow = lane & 15;
  int kbase = (lane >> 4) * 8;

  const float* qp = query + (size_t)(q0 + qrow) * 1024 + kbase;
  const unsigned short* up = U + qrow * 1024 + kbase;

  f32x4 acc[5];
  #pragma unroll
  for (int w = 0; w < 5; ++w) acc[w] = (f32x4){0.f, 0.f, 0.f, 0.f};

  #pragma unroll 4
  for (int kt = 0; kt < 32; ++kt) {
    const float* qk = qp + kt * 32;
    f32x4 lo = *(const f32x4*)qk;
    f32x4 hi = *(const f32x4*)(qk + 4);
    s16x8 bf;
    bf[0] = (short)f2bf(lo[0]); bf[1] = (short)f2bf(lo[1]);
    bf[2] = (short)f2bf(lo[2]); bf[3] = (short)f2bf(lo[3]);
    bf[4] = (short)f2bf(hi[0]); bf[5] = (short)f2bf(hi[1]);
    bf[6] = (short)f2bf(hi[2]); bf[7] = (short)f2bf(hi[3]);
    const unsigned short* uk = up + kt * 32;
    #pragma unroll
    for (int w = 0; w < 5; ++w) {
      s16x8 av = *(const s16x8*)(uk + w * 16384);   // row w*16 + qrow
      acc[w] = __builtin_amdgcn_mfma_f32_16x16x32_bf16(av, bf, acc[w], 0, 0, 0);
    }
  }

  // s_w = sum_{rows 0..9} c^2 - c_10^2 (rows 11..15 zero-padded)
  float sgn2 = ((lane >> 4) == 2) ? -1.f : 1.f;   // reg 2 of group 2 = row 10
  float sv[5];
  #pragma unroll
  for (int w = 0; w < 5; ++w) {
    float tcc = acc[w][0] * acc[w][0] + acc[w][1] * acc[w][1] +
                sgn2 * acc[w][2] * acc[w][2] + acc[w][3] * acc[w][3];
    tcc += __shfl_xor(tcc, 16);
    tcc += __shfl_xor(tcc, 32);
    sv[w] = tcc;
  }
  float mx = fmaxf(fmaxf(fmaxf(sv[0], sv[1]), fmaxf(sv[2], sv[3])), sv[4]);
  float sum = 0.f;
  #pragma unroll
  for (int w = 0; w < 5; ++w) sum += expf(sv[w] - mx);
  float lse = mx + logf(sum);
  if (lane < 16) {
    float* o = out + (size_t)(q0 + lane) * 5;
    #pragma unroll
    for (int w = 0; w < 5; ++w) o[w] = sv[w] - lse;
  }
}

extern "C" void kernel_launch(void* const* d_in, const int* in_sizes, int n_in,
                              void* d_out, int out_size, void* d_ws, size_t ws_size,
                              hipStream_t stream) {
  const float* support = (const float*)d_in[0];
  const int*   labels  = (const int*)d_in[1];
  const float* query   = (const float*)d_in[2];
  float* out = (float*)d_out;
  unsigned short* U = (unsigned short*)d_ws;

  int nq = in_sizes[2] / 1024;          // 16384
  int nwaves = nq / 16;                 // 1024
  int nblocks = (nwaves + 3) / 4;       // 256

  hipLaunchKernelGGL(dsn_prep, dim3(80), dim3(256), 0, stream, support, labels, U);
  hipLaunchKernelGGL(dsn_main, dim3(nblocks), dim3(256), 0, stream, query, U, out);
}

// Round 7
// 63.493 us; speedup vs baseline: 1.0962x; 1.0962x over previous
//
#include <hip/hip_runtime.h>
#include <stdint.h>

// DSN few-shot classifier, MI355X.
// out[q][w] = log_softmax_w( ||P9_w q||^2 ),  query-norm cancels in softmax.
// P9 = P_colspace - u_min u_min^T, so s_w = ||B^T q||^2 - (u_min . q)^2 with
// B = M L^{-T} D^{-1/2} (G = L D L^T) an exact ONB of colspace(M).
//
// R6: the 10-lane solve communicates via v_readlane (SGPR broadcast, ~4cyc)
// instead of __shfl/ds_bpermute (~60cyc + lgkmcnt). R5 counters showed the
// solve wave stalled ~95% on the shuffle chain (VALUBusy 1.18%).
//
// ws layout: [0, 163840) Upad : 80*1024 bf16 (way w -> rows 16w..16w+10).

typedef __attribute__((ext_vector_type(4))) float f32x4;
typedef __attribute__((ext_vector_type(8))) short s16x8;

__device__ __forceinline__ unsigned short f2bf(float f) {
  unsigned int u = __float_as_uint(f);
  u += 0x7FFFu + ((u >> 16) & 1u);   // round-to-nearest-even
  return (unsigned short)(u >> 16);
}

// broadcast lane l's value to all lanes via v_readlane (uniform result)
__device__ __forceinline__ float rdl(float v, int l) {
  return __uint_as_float(__builtin_amdgcn_readlane(__float_as_uint(v), l));
}

// int64 vs int32 one-hot labels detection (validated R0).
__device__ __forceinline__ bool labels_int64(const int* L) {
  int cnt = 0; bool oddz = true;
  #pragma unroll
  for (int t = 0; t < 20; ++t) {
    int v = L[t];
    if (t & 1) { if (v) oddz = false; }
    else       { if (v) cnt++; }
  }
  return oddz && (cnt == 2);
}

__device__ __forceinline__ int cls_of(const int* L, bool is64, int i) {
  int best = -0x7fffffff, c = 0;
  #pragma unroll
  for (int j = 0; j < 5; ++j) {
    int v = is64 ? L[i * 10 + 2 * j] : L[i * 5 + j];
    if (v > best) { best = v; c = j; }
  }
  return c;
}

// ---------------- Kernel A: fused prep, one block per Upad row -------------
__global__ __launch_bounds__(256) void dsn_prep(const float* __restrict__ support,
                                                const int* __restrict__ labels,
                                                unsigned short* __restrict__ U) {
  int b = blockIdx.x;              // 0..79
  int w = b >> 4, kk = b & 15;
  int t = threadIdx.x;
  unsigned short* Urow = U + b * 1024;
  if (kk >= 11) {                  // zero-pad rows (block-uniform early exit)
    #pragma unroll
    for (int j = 0; j < 4; ++j) Urow[t + 256 * j] = 0;
    return;
  }

  __shared__ float sup[10][1024];  // 40 KB: this way's support rows
  __shared__ float Gsm[100];       // Gram, fp32 (fp64-accumulated)
  __shared__ float Wsm[110];       // rows 0..9: basis coeffs; row 10: v_min/|Mv|
  __shared__ int   ids[10];        // support indices of this way

  // ---- class membership (wave 0) ----
  bool is64 = labels_int64(labels);
  if (t < 64) {
    int myc = (t < 50) ? cls_of(labels, is64, t) : -1;
    unsigned long long mask = __ballot(t < 50 && myc == w);
    if (t < 10) {
      unsigned long long m = mask;
      for (int i2 = 0; i2 < t; ++i2) m &= m - 1;
      ids[t] = __ffsll(m) - 1;
    }
  }
  __syncthreads();

  // ---- stage support rows into LDS (coalesced) ----
  #pragma unroll 1
  for (int s = 0; s < 10; ++s) {
    const float* src = support + (size_t)ids[s] * 1024;
    #pragma unroll
    for (int j = 0; j < 4; ++j) sup[s][t + 256 * j] = src[t + 256 * j];
  }
  __syncthreads();

  // ---- Gram: wave v handles pairs p = v, v+4, ... (fp64 acc, shfl reduce) --
  {
    int wv = t >> 6, lane = t & 63;
    #pragma unroll 1
    for (int p = wv; p < 55; p += 4) {
      int a2 = 0, pp = p;
      while (pp >= 10 - a2) { pp -= 10 - a2; a2++; }
      int b2 = a2 + pp;              // a2 <= b2
      double acc = 0.0;
      #pragma unroll
      for (int i2 = 0; i2 < 16; ++i2) {
        int d = lane + 64 * i2;
        acc += (double)sup[a2][d] * (double)sup[b2][d];
      }
      #pragma unroll
      for (int off = 32; off > 0; off >>= 1) acc += __shfl_xor(acc, off);
      if (lane == 0) {
        Gsm[a2 * 10 + b2] = (float)acc;
        Gsm[b2 * 10 + a2] = (float)acc;
      }
    }
  }
  __syncthreads();

  // ---- subspace solve: lanes 0-9 of wave 0, readlane-based cooperative ----
  if (t < 10) {
    int li = t;                      // my row
    float g[10];
    #pragma unroll
    for (int k = 0; k < 10; ++k) g[k] = Gsm[li * 10 + k];

    // Gershgorin bracket (uniform after readlane-reduce)
    float diag = g[0];
    #pragma unroll
    for (int k = 1; k < 10; ++k) diag = (li == k) ? g[k] : diag;
    float asum = 0.f;
    #pragma unroll
    for (int k = 0; k < 10; ++k) asum += fabsf(g[k]);
    float loi = diag - (asum - fabsf(diag)), hii = diag;
    float lo = 1e30f, hi = 1e30f;
    #pragma unroll
    for (int u = 0; u < 10; ++u) {
      lo = fminf(lo, rdl(loi, u));
      hi = fminf(hi, rdl(hii, u));
    }
    lo = fmaxf(lo, 0.f);
    hi = hi + 1.f;

    // bisection on Sylvester inertia (distributed LDL^T), 10 rounds.
    // mid/dj/neg are uniform -> scalar branch, no divergence.
    #pragma unroll 1
    for (int round = 0; round < 10; ++round) {
      float mid = 0.5f * (lo + hi);
      float a[10];
      #pragma unroll
      for (int k = 0; k < 10; ++k) a[k] = (li == k) ? (g[k] - mid) : g[k];
      int neg = 0;
      #pragma unroll
      for (int j = 0; j < 10; ++j) {
        float dj = rdl(a[j], j);
        if (fabsf(dj) < 1e-4f) dj = -1e-4f;   // inertia guard
        neg += (dj < 0.f) ? 1 : 0;
        float inv = 1.f / dj;
        float lij = a[j] * inv;
        #pragma unroll
        for (int k = j + 1; k < 10; ++k) {
          float ajk = rdl(a[k], j);
          if (li > j) a[k] -= lij * ajk;
        }
      }
      if (neg == 0) lo = mid; else hi = mid;   // scalar-uniform
    }
    float sigma = lo - (hi - lo) - 0.5f;       // lambda_min - sigma in ~[0.5+w, 0.5+2w]

    // factorize (G - sigma I) = L D L^T; keep my L-row, my 1/pivot
    float a[10], l[10], dinv_mine = 1.f;
    #pragma unroll
    for (int k = 0; k < 10; ++k) a[k] = (li == k) ? (g[k] - sigma) : g[k];
    #pragma unroll
    for (int j = 0; j < 10; ++j) {
      float dj = rdl(a[j], j);
      float inv = 1.f / dj;
      dinv_mine = (li == j) ? inv : dinv_mine;
      float lij = a[j] * inv;
      l[j] = (li > j) ? lij : 0.f;
      #pragma unroll
      for (int k = j + 1; k < 10; ++k) {
        float ajk = rdl(a[k], j);
        if (li > j) a[k] -= lij * ajk;
      }
    }
    // transpose once: lt[j] = L[j][li] (needed for back-solves, li<j)
    float lt[10];
    #pragma unroll
    for (int j = 0; j < 10; ++j) lt[j] = 0.f;
    #pragma unroll
    for (int j = 1; j < 10; ++j) {
      #pragma unroll
      for (int k = 0; k < j; ++k) {
        float v = rdl(l[k], j);
        lt[j] = (li == k) ? v : lt[j];
      }
    }

    // inverse iteration, 10 solves, normalize each iter (y = comp li)
    float y = 1.f;
    #pragma unroll 1
    for (int itr = 0; itr < 10; ++itr) {
      #pragma unroll
      for (int j = 0; j < 9; ++j) {          // forward: L z = y
        float yj = rdl(y, j);
        if (li > j) y -= l[j] * yj;
      }
      y *= dinv_mine;                        // D
      #pragma unroll
      for (int j = 9; j >= 1; --j) {         // back: L^T x = z
        float xj = rdl(y, j);
        if (li < j) y -= lt[j] * xj;
      }
      float am = fabsf(y), mx = 0.f;
      #pragma unroll
      for (int u = 0; u < 10; ++u) mx = fmaxf(mx, rdl(am, u));
      y *= (1.f / mx);
    }

    // row 10: v / ||M v||, ||M v||^2 = v^T G v  (scale-invariant)
    float gv = 0.f;
    #pragma unroll
    for (int k = 0; k < 10; ++k) gv += g[k] * rdl(y, k);
    float contrib = gv * y, denom = 0.f;
    #pragma unroll
    for (int u = 0; u < 10; ++u) denom += rdl(contrib, u);
    float sc = 1.f / sqrtf(denom);
    Wsm[100 + li] = y * sc;

    // factorize G = L D L^T (sigma=0); keep pivots (uniform) + L row
    float dv[10];
    #pragma unroll
    for (int k = 0; k < 10; ++k) a[k] = g[k];
    #pragma unroll
    for (int j = 0; j < 10; ++j) {
      float dj = rdl(a[j], j);
      dv[j] = dj;
      float inv = 1.f / dj;
      float lij = a[j] * inv;
      l[j] = (li > j) ? lij : 0.f;
      #pragma unroll
      for (int k = j + 1; k < 10; ++k) {
        float ajk = rdl(a[k], j);
        if (li > j) a[k] -= lij * ajk;
      }
    }
    #pragma unroll
    for (int j = 0; j < 10; ++j) lt[j] = 0.f;
    #pragma unroll
    for (int j = 1; j < 10; ++j) {
      #pragma unroll
      for (int k = 0; k < j; ++k) {
        float v = rdl(l[k], j);
        lt[j] = (li == k) ? v : lt[j];
      }
    }

    // X = L^{-T} (lane li holds row li), all 10 columns
    float X[10];
    #pragma unroll
    for (int r = 0; r < 10; ++r) X[r] = (li == r) ? 1.f : 0.f;
    #pragma unroll
    for (int j = 9; j >= 1; --j) {
      #pragma unroll
      for (int r = j; r < 10; ++r) {
        float xjr = rdl(X[r], j);
        if (li < j) X[r] -= lt[j] * xjr;
      }
    }
    // basis r coeffs = col r of L^{-T} D^{-1/2}: Wsm[r*10+s] = X[s][r]/sqrt(d_r)
    #pragma unroll
    for (int r = 0; r < 10; ++r)
      Wsm[r * 10 + li] = X[r] * (1.f / sqrtf(dv[r]));
  }
  __syncthreads();

  // ---- materialize my Upad row from LDS ----
  float wv10[10];
  #pragma unroll
  for (int s = 0; s < 10; ++s) wv10[s] = Wsm[kk * 10 + s];
  #pragma unroll
  for (int j = 0; j < 4; ++j) {
    int d = t + 256 * j;
    float sum = 0.f;
    #pragma unroll
    for (int s = 0; s < 10; ++s) sum += sup[s][d] * wv10[s];
    Urow[d] = f2bf(sum);
  }
}

// ---------------- Kernel B: main — MFMA coeffs + log_softmax ---------------
// 16 queries per wave. A = Upad (5 row-tiles, one per way), B = Q^T fragment.
// D[row=channel][col=query]: col = lane&15, row = (lane>>4)*4 + reg  (m89).
// Row 10 (u_min) lives at lane-group 2, reg 2 -> its square is SUBTRACTED.
__global__ __launch_bounds__(256) void dsn_main(const float* __restrict__ query,
                                                const unsigned short* __restrict__ U,
                                                float* __restrict__ out) {
  int wid  = blockIdx.x * 4 + (threadIdx.x >> 6);
  int lane = threadIdx.x & 63;
  int q0   = wid * 16;
  int qrow = lane & 15;
  int kbase = (lane >> 4) * 8;

  const float* qp = query + (size_t)(q0 + qrow) * 1024 + kbase;
  const unsigned short* up = U + qrow * 1024 + kbase;

  f32x4 acc[5];
  #pragma unroll
  for (int w = 0; w < 5; ++w) acc[w] = (f32x4){0.f, 0.f, 0.f, 0.f};

  #pragma unroll 4
  for (int kt = 0; kt < 32; ++kt) {
    const float* qk = qp + kt * 32;
    f32x4 lo = *(const f32x4*)qk;
    f32x4 hi = *(const f32x4*)(qk + 4);
    s16x8 bf;
    bf[0] = (short)f2bf(lo[0]); bf[1] = (short)f2bf(lo[1]);
    bf[2] = (short)f2bf(lo[2]); bf[3] = (short)f2bf(lo[3]);
    bf[4] = (short)f2bf(hi[0]); bf[5] = (short)f2bf(hi[1]);
    bf[6] = (short)f2bf(hi[2]); bf[7] = (short)f2bf(hi[3]);
    const unsigned short* uk = up + kt * 32;
    #pragma unroll
    for (int w = 0; w < 5; ++w) {
      s16x8 av = *(const s16x8*)(uk + w * 16384);   // row w*16 + qrow
      acc[w] = __builtin_amdgcn_mfma_f32_16x16x32_bf16(av, bf, acc[w], 0, 0, 0);
    }
  }

  // s_w = sum_{rows 0..9} c^2 - c_10^2 (rows 11..15 zero-padded)
  float sgn2 = ((lane >> 4) == 2) ? -1.f : 1.f;   // reg 2 of group 2 = row 10
  float sv[5];
  #pragma unroll
  for (int w = 0; w < 5; ++w) {
    float tcc = acc[w][0] * acc[w][0] + acc[w][1] * acc[w][1] +
                sgn2 * acc[w][2] * acc[w][2] + acc[w][3] * acc[w][3];
    tcc += __shfl_xor(tcc, 16);
    tcc += __shfl_xor(tcc, 32);
    sv[w] = tcc;
  }
  float mx = fmaxf(fmaxf(fmaxf(sv[0], sv[1]), fmaxf(sv[2], sv[3])), sv[4]);
  float sum = 0.f;
  #pragma unroll
  for (int w = 0; w < 5; ++w) sum += expf(sv[w] - mx);
  float lse = mx + logf(sum);
  if (lane < 16) {
    float* o = out + (size_t)(q0 + lane) * 5;
    #pragma unroll
    for (int w = 0; w < 5; ++w) o[w] = sv[w] - lse;
  }
}

extern "C" void kernel_launch(void* const* d_in, const int* in_sizes, int n_in,
                              void* d_out, int out_size, void* d_ws, size_t ws_size,
                              hipStream_t stream) {
  const float* support = (const float*)d_in[0];
  const int*   labels  = (const int*)d_in[1];
  const float* query   = (const float*)d_in[2];
  float* out = (float*)d_out;
  unsigned short* U = (unsigned short*)d_ws;

  int nq = in_sizes[2] / 1024;          // 16384
  int nwaves = nq / 16;                 // 1024
  int nblocks = (nwaves + 3) / 4;       // 256

  hipLaunchKernelGGL(dsn_prep, dim3(80), dim3(256), 0, stream, support, labels, U);
  hipLaunchKernelGGL(dsn_main, dim3(nblocks), dim3(256), 0, stream, query, U, out);
}